// Round 1
// baseline (1038.726 us; speedup 1.0000x reference)
//
#include <hip/hip_runtime.h>
#include <hip/hip_bf16.h>

// HeteroGCN: 3x SAGEConv(mean) on a gene/trait graph.
// out_gene  = x_gene@(Ws_gg+Ws_tg) + b_gg+b_tg + seg_mean_gg(x_gene)@Wn_gg + seg_mean_tg(x_trait)@Wn_tg
// out_trait = x_trait@Ws_gt + b_gt + seg_mean_gt(x_gene)@Wn_gt
// Trick: (segsum(x[src])/deg)@Wn == segsum((x@Wn)[src])/deg  -> transform first, then
// scatter y[src]*inv_deg[dst] straight into out. One shared y buffer in d_ws.

#define D 128
#define NG 100000
#define NT 100000

constexpr int ROWS_PER_BLOCK = 32;

// out[row][c] = sum_k x[row][k] * (W1[k][c] (+ W2[k][c])) (+ b1[c] (+ b2[c]))
__global__ __launch_bounds__(256) void xw_kernel(
    const float* __restrict__ x, int n_rows,
    const float* __restrict__ W1, const float* __restrict__ W2,
    const float* __restrict__ b1, const float* __restrict__ b2,
    float* __restrict__ out)
{
    __shared__ float Wl[D][D];                 // 64 KiB
    __shared__ float Xl[ROWS_PER_BLOCK][D];    // 16 KiB
    const int t = threadIdx.x;

    // stage W (+W2) into LDS, float4 coalesced
    {
        const float4* w1 = (const float4*)W1;
        const float4* w2 = (const float4*)W2;
        float4* wl = (float4*)&Wl[0][0];
        for (int i = t; i < D * D / 4; i += 256) {
            float4 v = w1[i];
            if (w2) { float4 u = w2[i]; v.x += u.x; v.y += u.y; v.z += u.z; v.w += u.w; }
            wl[i] = v;
        }
    }
    const int row0 = blockIdx.x * ROWS_PER_BLOCK;
    const int nrow = min(ROWS_PER_BLOCK, n_rows - row0);
    // stage X tile
    {
        const float4* xg = (const float4*)(x + (size_t)row0 * D);
        float4* xl = (float4*)&Xl[0][0];
        const int nv = nrow * (D / 4);
        for (int i = t; i < nv; i += 256) xl[i] = xg[i];
    }
    __syncthreads();

    const int cg = t & 31;     // 32 col-groups of 4 cols
    const int rg = t >> 5;     // 8 row-groups of 4 rows
    const int c0 = cg * 4;
    constexpr int R = 4;
    const int rbase = rg * R;

    float4 bv = make_float4(0.f, 0.f, 0.f, 0.f);
    if (b1) { float4 u = *(const float4*)(b1 + c0); bv.x += u.x; bv.y += u.y; bv.z += u.z; bv.w += u.w; }
    if (b2) { float4 u = *(const float4*)(b2 + c0); bv.x += u.x; bv.y += u.y; bv.z += u.z; bv.w += u.w; }

    float acc[R][4];
#pragma unroll
    for (int i = 0; i < R; ++i) {
        acc[i][0] = bv.x; acc[i][1] = bv.y; acc[i][2] = bv.z; acc[i][3] = bv.w;
    }

    for (int k = 0; k < D; k += 4) {
        float4 w0 = *(const float4*)&Wl[k + 0][c0];
        float4 w1 = *(const float4*)&Wl[k + 1][c0];
        float4 w2 = *(const float4*)&Wl[k + 2][c0];
        float4 w3 = *(const float4*)&Wl[k + 3][c0];
#pragma unroll
        for (int i = 0; i < R; ++i) {
            float4 xv = *(const float4*)&Xl[rbase + i][k];
            acc[i][0] += xv.x * w0.x + xv.y * w1.x + xv.z * w2.x + xv.w * w3.x;
            acc[i][1] += xv.x * w0.y + xv.y * w1.y + xv.z * w2.y + xv.w * w3.y;
            acc[i][2] += xv.x * w0.z + xv.y * w1.z + xv.z * w2.z + xv.w * w3.z;
            acc[i][3] += xv.x * w0.w + xv.y * w1.w + xv.z * w2.w + xv.w * w3.w;
        }
    }

#pragma unroll
    for (int i = 0; i < R; ++i) {
        const int r = rbase + i;
        if (r < nrow) {
            float4 v = make_float4(acc[i][0], acc[i][1], acc[i][2], acc[i][3]);
            *(float4*)(out + (size_t)(row0 + r) * D + c0) = v;
        }
    }
}

__global__ __launch_bounds__(256) void deg_kernel(
    const int* __restrict__ dst, int* __restrict__ deg, int nE)
{
    int i = blockIdx.x * blockDim.x + threadIdx.x;
    if (i < nE) atomicAdd(&deg[dst[i]], 1);
}

// one 64-lane wave per edge; lane handles cols {lane, lane+64}
__global__ __launch_bounds__(256) void scatter_kernel(
    const float* __restrict__ y, const int* __restrict__ src, const int* __restrict__ dst,
    const int* __restrict__ deg, float* __restrict__ out, int nE)
{
    const int gid = blockIdx.x * blockDim.x + threadIdx.x;
    const int e = gid >> 6;
    const int lane = threadIdx.x & 63;
    if (e >= nE) return;
    const int s = src[e];
    const int d = dst[e];
    const float inv = 1.0f / (float)max(deg[d], 1);
    const float* ys = y + (size_t)s * D;
    float* od = out + (size_t)d * D;
    atomicAdd(&od[lane], ys[lane] * inv);
    atomicAdd(&od[lane + 64], ys[lane + 64] * inv);
}

extern "C" void kernel_launch(void* const* d_in, const int* in_sizes, int n_in,
                              void* d_out, int out_size, void* d_ws, size_t ws_size,
                              hipStream_t stream)
{
    const float* x_gene  = (const float*)d_in[0];
    const float* x_trait = (const float*)d_in[1];
    const int* src_gg = (const int*)d_in[2];
    const int* dst_gg = (const int*)d_in[3];
    const int* src_gt = (const int*)d_in[4];
    const int* dst_gt = (const int*)d_in[5];
    const int* src_tg = (const int*)d_in[6];
    const int* dst_tg = (const int*)d_in[7];
    const float* Wn_gg = (const float*)d_in[8];
    const float* Ws_gg = (const float*)d_in[9];
    const float* b_gg  = (const float*)d_in[10];
    const float* Wn_gt = (const float*)d_in[11];
    const float* Ws_gt = (const float*)d_in[12];
    const float* b_gt  = (const float*)d_in[13];
    const float* Wn_tg = (const float*)d_in[14];
    const float* Ws_tg = (const float*)d_in[15];
    const float* b_tg  = (const float*)d_in[16];

    const int nE_gg = in_sizes[2];
    const int nE_gt = in_sizes[4];
    const int nE_tg = in_sizes[6];

    float* out_gene  = (float*)d_out;
    float* out_trait = (float*)d_out + (size_t)NG * D;

    // workspace layout: y [max(NG,NT) x D] f32, then deg_gg, deg_gt, deg_tg (int)
    float* y = (float*)d_ws;
    const size_t y_bytes = (size_t)NG * D * sizeof(float);
    int* deg_gg = (int*)((char*)d_ws + y_bytes);
    int* deg_gt = deg_gg + NG;
    int* deg_tg = deg_gt + NT;

    // 1) zero degree counters
    hipMemsetAsync(deg_gg, 0, (size_t)(NG + NT + NG) * sizeof(int), stream);

    // 2) degrees
    {
        const int tb = 256;
        deg_kernel<<<(nE_gg + tb - 1) / tb, tb, 0, stream>>>(dst_gg, deg_gg, nE_gg);
        deg_kernel<<<(nE_gt + tb - 1) / tb, tb, 0, stream>>>(dst_gt, deg_gt, nE_gt);
        deg_kernel<<<(nE_tg + tb - 1) / tb, tb, 0, stream>>>(dst_tg, deg_tg, nE_tg);
    }

    const int gblocks = (NG + ROWS_PER_BLOCK - 1) / ROWS_PER_BLOCK;
    const int tblocks = (NT + ROWS_PER_BLOCK - 1) / ROWS_PER_BLOCK;

    // 3) self terms (overwrite out -> deterministic across replays)
    xw_kernel<<<gblocks, 256, 0, stream>>>(x_gene, NG, Ws_gg, Ws_tg, b_gg, b_tg, out_gene);
    xw_kernel<<<tblocks, 256, 0, stream>>>(x_trait, NT, Ws_gt, nullptr, b_gt, nullptr, out_trait);

    // 4) per-etype: y = x_src @ Wn, then scatter y[src]*inv_deg[dst] into out
    const int sc_tb = 256;  // 4 waves/block, 1 wave per edge
    // gg: gene -> gene
    xw_kernel<<<gblocks, 256, 0, stream>>>(x_gene, NG, Wn_gg, nullptr, nullptr, nullptr, y);
    scatter_kernel<<<((size_t)nE_gg * 64 + sc_tb - 1) / sc_tb, sc_tb, 0, stream>>>(
        y, src_gg, dst_gg, deg_gg, out_gene, nE_gg);
    // gt: gene -> trait
    xw_kernel<<<gblocks, 256, 0, stream>>>(x_gene, NG, Wn_gt, nullptr, nullptr, nullptr, y);
    scatter_kernel<<<((size_t)nE_gt * 64 + sc_tb - 1) / sc_tb, sc_tb, 0, stream>>>(
        y, src_gt, dst_gt, deg_gt, out_trait, nE_gt);
    // tg: trait -> gene
    xw_kernel<<<tblocks, 256, 0, stream>>>(x_trait, NT, Wn_tg, nullptr, nullptr, nullptr, y);
    scatter_kernel<<<((size_t)nE_tg * 64 + sc_tb - 1) / sc_tb, sc_tb, 0, stream>>>(
        y, src_tg, dst_tg, deg_tg, out_gene, nE_tg);
}